// Round 24
// baseline (74.994 us; speedup 1.0000x reference)
//
#include <hip/hip_runtime.h>
#include <hip/hip_bf16.h>
#include <math.h>

#define NF     16
#define INF    1024
#define NPROTO 4096
#define NROWS  16384

typedef __attribute__((ext_vector_type(8))) short short8;   // 8 bf16 (4 VGPRs)
typedef __attribute__((ext_vector_type(4))) float f32x4;
typedef __attribute__((ext_vector_type(2))) float f32x2;

__device__ __forceinline__ float bf16_rne(float x) {
    unsigned u = __float_as_uint(x);
    unsigned r = (u + 0x7FFFu + ((u >> 16) & 1u)) & 0xFFFF0000u;
    return __uint_as_float(r);
}
__device__ __forceinline__ unsigned short bf16_hi(float v) {
    unsigned u = __float_as_uint(v);
    return (unsigned short)((u + 0x7FFFu + ((u >> 16) & 1u)) >> 16);
}
// split f32 v into bf16 hi + bf16 lo (v ~= hi + lo)
__device__ __forceinline__ void split_bf16(float v, unsigned short& hi, unsigned short& lo) {
    unsigned u  = __float_as_uint(v);
    unsigned r  = u + 0x7FFFu + ((u >> 16) & 1u);
    hi = (unsigned short)(r >> 16);
    float hf = __uint_as_float(r & 0xFFFF0000u);
    lo = bf16_hi(v - hf);
}
__device__ __forceinline__ float sigmoid5(float z) {
    return 1.0f / (1.0f + __expf(-5.0f * z));
}

// ---- B-fragment precompute: feat -> bf16 hi/lo MFMA fragments ----
__global__ __launch_bounds__(256) void bfrag_kernel(
    const float* __restrict__ feat,
    unsigned short* __restrict__ BFh, unsigned short* __restrict__ BFl)
{
    const int t = blockIdx.x * 256 + threadIdx.x;    // 0..2047
    const int kstep = t >> 6, lane = t & 63;
    const int n = lane & 15, b = lane >> 4;
    const float* src = feat + (size_t)n * INF + kstep * 32 + b * 8;
    float4 v0 = *(const float4*)(src);
    float4 v1 = *(const float4*)(src + 4);
    unsigned short h[8], l[8];
    split_bf16(v0.x, h[0], l[0]); split_bf16(v0.y, h[1], l[1]);
    split_bf16(v0.z, h[2], l[2]); split_bf16(v0.w, h[3], l[3]);
    split_bf16(v1.x, h[4], l[4]); split_bf16(v1.y, h[5], l[5]);
    split_bf16(v1.z, h[6], l[6]); split_bf16(v1.w, h[7], l[7]);
#pragma unroll
    for (int e = 0; e < 8; ++e) { BFh[t * 8 + e] = h[e]; BFl[t * 8 + e] = l[e]; }
}

// ---- prep_pe: R22 pe branch only (K-split, 4 waves/block), Ph hi-plane ----
__global__ __launch_bounds__(256, 4) void prep_pe(
    const float* __restrict__ proto,
    const float* __restrict__ theta, const float* __restrict__ alpha,
    const float* __restrict__ beta,
    const unsigned short* __restrict__ BFh, const unsigned short* __restrict__ BFl,
    unsigned short* __restrict__ Ph)
{
    __shared__ f32x4 red[4][64];
    const int lane = threadIdx.x & 63;
    const int w    = threadIdx.x >> 6;
    const int m = lane & 15, b = lane >> 4;
    const int rowbase = blockIdx.x * 16;
    const float* rowp = proto + (size_t)(rowbase + m) * INF;

    f32x4 acc = {0.f, 0.f, 0.f, 0.f};
#pragma unroll
    for (int gi = 0; gi < 4; ++gi) {
        const int g = w * 4 + gi;   // 64-elem quant group; ksteps 2g, 2g+1
        const float* pg = rowp + g * 64 + b * 8;
        float4 v0 = *(const float4*)(pg);
        float4 v1 = *(const float4*)(pg + 4);
        float4 v2 = *(const float4*)(pg + 32);
        float4 v3 = *(const float4*)(pg + 36);
        float w0 = bf16_rne(v0.x), w1 = bf16_rne(v0.y), w2 = bf16_rne(v0.z), w3 = bf16_rne(v0.w);
        float w4 = bf16_rne(v1.x), w5 = bf16_rne(v1.y), w6 = bf16_rne(v1.z), w7 = bf16_rne(v1.w);
        float w8 = bf16_rne(v2.x), w9 = bf16_rne(v2.y), wa = bf16_rne(v2.z), wb = bf16_rne(v2.w);
        float wc = bf16_rne(v3.x), wd = bf16_rne(v3.y), we = bf16_rne(v3.z), wf = bf16_rne(v3.w);
        float p0 = ((fabsf(w0) + fabsf(w1)) + fabsf(w2)) + fabsf(w3);
        float p1 = ((fabsf(w4) + fabsf(w5)) + fabsf(w6)) + fabsf(w7);
        float p2 = ((fabsf(w8) + fabsf(w9)) + fabsf(wa)) + fabsf(wb);
        float p3 = ((fabsf(wc) + fabsf(wd)) + fabsf(we)) + fabsf(wf);
        float p = ((p0 + p1) + p2) + p3;
        p += __shfl_xor(p, 16, 64);
        p += __shfl_xor(p, 32, 64);
        float scale = fmaxf(bf16_rne(p * (1.0f / 64.0f)), 1e-8f);
        float inv = 1.0f / scale;
        short8 A0, A1;
        A0[0] = (short)bf16_hi(fminf(fmaxf(rintf(bf16_rne(w0 * inv)), -1.f), 1.f) * scale);
        A0[1] = (short)bf16_hi(fminf(fmaxf(rintf(bf16_rne(w1 * inv)), -1.f), 1.f) * scale);
        A0[2] = (short)bf16_hi(fminf(fmaxf(rintf(bf16_rne(w2 * inv)), -1.f), 1.f) * scale);
        A0[3] = (short)bf16_hi(fminf(fmaxf(rintf(bf16_rne(w3 * inv)), -1.f), 1.f) * scale);
        A0[4] = (short)bf16_hi(fminf(fmaxf(rintf(bf16_rne(w4 * inv)), -1.f), 1.f) * scale);
        A0[5] = (short)bf16_hi(fminf(fmaxf(rintf(bf16_rne(w5 * inv)), -1.f), 1.f) * scale);
        A0[6] = (short)bf16_hi(fminf(fmaxf(rintf(bf16_rne(w6 * inv)), -1.f), 1.f) * scale);
        A0[7] = (short)bf16_hi(fminf(fmaxf(rintf(bf16_rne(w7 * inv)), -1.f), 1.f) * scale);
        A1[0] = (short)bf16_hi(fminf(fmaxf(rintf(bf16_rne(w8 * inv)), -1.f), 1.f) * scale);
        A1[1] = (short)bf16_hi(fminf(fmaxf(rintf(bf16_rne(w9 * inv)), -1.f), 1.f) * scale);
        A1[2] = (short)bf16_hi(fminf(fmaxf(rintf(bf16_rne(wa * inv)), -1.f), 1.f) * scale);
        A1[3] = (short)bf16_hi(fminf(fmaxf(rintf(bf16_rne(wb * inv)), -1.f), 1.f) * scale);
        A1[4] = (short)bf16_hi(fminf(fmaxf(rintf(bf16_rne(wc * inv)), -1.f), 1.f) * scale);
        A1[5] = (short)bf16_hi(fminf(fmaxf(rintf(bf16_rne(wd * inv)), -1.f), 1.f) * scale);
        A1[6] = (short)bf16_hi(fminf(fmaxf(rintf(bf16_rne(we * inv)), -1.f), 1.f) * scale);
        A1[7] = (short)bf16_hi(fminf(fmaxf(rintf(bf16_rne(wf * inv)), -1.f), 1.f) * scale);
        const short8 Bh0 = *(const short8*)(BFh + ((size_t)(2 * g) * 64 + lane) * 8);
        const short8 Bl0 = *(const short8*)(BFl + ((size_t)(2 * g) * 64 + lane) * 8);
        const short8 Bh1 = *(const short8*)(BFh + ((size_t)(2 * g + 1) * 64 + lane) * 8);
        const short8 Bl1 = *(const short8*)(BFl + ((size_t)(2 * g + 1) * 64 + lane) * 8);
        acc = __builtin_amdgcn_mfma_f32_16x16x32_bf16(A0, Bh0, acc, 0, 0, 0);
        acc = __builtin_amdgcn_mfma_f32_16x16x32_bf16(A0, Bl0, acc, 0, 0, 0);
        acc = __builtin_amdgcn_mfma_f32_16x16x32_bf16(A1, Bh1, acc, 0, 0, 0);
        acc = __builtin_amdgcn_mfma_f32_16x16x32_bf16(A1, Bl1, acc, 0, 0, 0);
    }

    red[w][lane] = acc;
    __syncthreads();
    if (w == 0) {
        f32x4 a0 = red[0][lane], a1 = red[1][lane], a2 = red[2][lane], a3 = red[3][lane];
        f32x4 tot = (a0 + a1) + (a2 + a3);
        const float th = fabsf(theta[0]);
        const float al = fabsf(alpha[0]);
        const float be = fabsf(beta[0]);
#pragma unroll
        for (int reg = 0; reg < 4; ++reg) {
            const int row = rowbase + b * 4 + reg;
            float pf = tot[reg];
            float ps = sigmoid5(pf);
            float pa = pf * ps;
            Ph[row * 32 + m]      = bf16_hi(th * pa - al * (1.0f - ps));
            Ph[row * 32 + 16 + m] = bf16_hi(-be * pa);
        }
    }
}

// ---- fused main: xe projection + GEMM + store, one dispatch ----
// Block = 4 waves owns 16 output rows x ALL 4096 cols.
// Phase 1 (R22 xe verbatim): wave w ksteps [8w,8w+8) -> LDS reduce ->
//   wave0 sigmoid/split -> 2 KB Xe tile in LDS. x read ONCE per row.
// Phase 2 (R23 walk): wave w owns cols [1024w,1024w+1024) as 8 chunks of
//   128: 8 t-tiles x (Ph-hi load + 2 MFMA) -> wave-private swizzled ldsT[w]
//   -> 16 NT f32x2 row stores (512 B contiguous).
// LDS 38 KB -> 4 blocks/CU = 16 waves/CU = 4 w/SIMD (R14-class occupancy).
__global__ __launch_bounds__(256, 4) void fused_main(
    const float* __restrict__ x,
    const unsigned short* __restrict__ BFh, const unsigned short* __restrict__ BFl,
    const unsigned short* __restrict__ Ph,
    float* __restrict__ out)
{
    __shared__ float ldsT[4][16][128];               // 32 KB transpose bufs
    __shared__ f32x4 red[4][64];                     // 4 KB reduce
    __shared__ unsigned short XeH[16][32], XeL[16][32]; // 2 KB Xe tile

    const int lane = threadIdx.x & 63;
    const int w    = threadIdx.x >> 6;
    const int m = lane & 15, b = lane >> 4;
    const int rowbase = blockIdx.x * 16;
    const float* rowp = x + (size_t)(rowbase + m) * INF;

    // ---- Phase 1: Xe projection (K-split across 4 waves) ----
    f32x4 acc = {0.f, 0.f, 0.f, 0.f};
#pragma unroll
    for (int ki = 0; ki < 8; ++ki) {
        const int kstep = w * 8 + ki;
        const float* pk = rowp + kstep * 32 + b * 8;
        float4 v0 = *(const float4*)(pk);
        float4 v1 = *(const float4*)(pk + 4);
        unsigned short h0,l0,h1,l1,h2,l2,h3,l3,h4,l4,h5,l5,h6,l6,h7,l7;
        split_bf16(v0.x, h0, l0); split_bf16(v0.y, h1, l1);
        split_bf16(v0.z, h2, l2); split_bf16(v0.w, h3, l3);
        split_bf16(v1.x, h4, l4); split_bf16(v1.y, h5, l5);
        split_bf16(v1.z, h6, l6); split_bf16(v1.w, h7, l7);
        short8 Ah, Al;
        Ah[0]=(short)h0; Ah[1]=(short)h1; Ah[2]=(short)h2; Ah[3]=(short)h3;
        Ah[4]=(short)h4; Ah[5]=(short)h5; Ah[6]=(short)h6; Ah[7]=(short)h7;
        Al[0]=(short)l0; Al[1]=(short)l1; Al[2]=(short)l2; Al[3]=(short)l3;
        Al[4]=(short)l4; Al[5]=(short)l5; Al[6]=(short)l6; Al[7]=(short)l7;
        const short8 Bh = *(const short8*)(BFh + ((size_t)kstep * 64 + lane) * 8);
        const short8 Bl = *(const short8*)(BFl + ((size_t)kstep * 64 + lane) * 8);
        acc = __builtin_amdgcn_mfma_f32_16x16x32_bf16(Ah, Bh, acc, 0, 0, 0);
        acc = __builtin_amdgcn_mfma_f32_16x16x32_bf16(Ah, Bl, acc, 0, 0, 0);
        acc = __builtin_amdgcn_mfma_f32_16x16x32_bf16(Al, Bh, acc, 0, 0, 0);
        acc = __builtin_amdgcn_mfma_f32_16x16x32_bf16(Al, Bl, acc, 0, 0, 0);
    }
    red[w][lane] = acc;
    __syncthreads();
    if (w == 0) {
        f32x4 a0 = red[0][lane], a1 = red[1][lane], a2 = red[2][lane], a3 = red[3][lane];
        f32x4 tot = (a0 + a1) + (a2 + a3);
#pragma unroll
        for (int reg = 0; reg < 4; ++reg) {
            const int row = b * 4 + reg;
            float xf = tot[reg];
            float xs = sigmoid5(xf);
            unsigned short h0,l0,h1,l1;
            split_bf16(xf * xs, h0, l0);
            split_bf16(1.0f - xs, h1, l1);
            XeH[row][m]      = h0;  XeL[row][m]      = l0;
            XeH[row][16 + m] = h1;  XeL[row][16 + m] = l1;
        }
    }
    __syncthreads();

    // ---- Phase 2: GEMM walk over this wave's 1024-col span ----
    const short8 Bh = *(const short8*)&XeH[m][b * 8];
    const short8 Bl = *(const short8*)&XeL[m][b * 8];
    const int wsw = 4 * (m & 7);
    float* myrow = &ldsT[w][m][0];
    const float* src = &ldsT[w][0][0];

#pragma unroll 1
    for (int c = 0; c < 8; ++c) {
        const int ob = w * 1024 + c * 128;
#pragma unroll
        for (int t = 0; t < 8; ++t) {
            const size_t aoff = (size_t)(ob + t * 16 + m) * 32 + b * 8;
            const short8 Ah = *(const short8*)(Ph + aoff);
            f32x4 a2 = {0.f, 0.f, 0.f, 0.f};
            a2 = __builtin_amdgcn_mfma_f32_16x16x32_bf16(Ah, Bh, a2, 0, 0, 0);
            a2 = __builtin_amdgcn_mfma_f32_16x16x32_bf16(Ah, Bl, a2, 0, 0, 0);
            *(f32x4*)(myrow + ((t * 16 + b * 4) ^ wsw)) = a2;   // 4-aligned XOR
        }
        // wave-private ldsT[w]: no barrier, lgkmcnt covers RAW
#pragma unroll
        for (int r = 0; r < 16; ++r) {
            f32x2 v = *(const f32x2*)(src + r * 128 + ((lane * 2) ^ (4 * (r & 7))));
            f32x2* dst = (f32x2*)(out + (size_t)(rowbase + r) * NPROTO + ob + lane * 2);
            __builtin_nontemporal_store(v, dst);
        }
    }
}

extern "C" void kernel_launch(void* const* d_in, const int* in_sizes, int n_in,
                              void* d_out, int out_size, void* d_ws, size_t ws_size,
                              hipStream_t stream) {
    const float* x     = (const float*)d_in[0];
    const float* feat  = (const float*)d_in[1];
    const float* proto = (const float*)d_in[2];
    const float* theta = (const float*)d_in[3];
    const float* alpha = (const float*)d_in[4];
    const float* beta  = (const float*)d_in[5];
    float* out = (float*)d_out;

    unsigned short* Ph  = (unsigned short*)d_ws;          // 256 KiB
    unsigned short* BFh = Ph + (size_t)NPROTO * 32;       // 32 KiB
    unsigned short* BFl = BFh + (size_t)2048 * 8;         // 32 KiB

    bfrag_kernel<<<dim3(8), 256, 0, stream>>>(feat, BFh, BFl);
    prep_pe<<<dim3(NPROTO / 16), 256, 0, stream>>>(proto, theta, alpha, beta, BFh, BFl, Ph);
    fused_main<<<dim3(NROWS / 16), 256, 0, stream>>>(x, BFh, BFl, Ph, out);
}

// Round 25
// 70.717 us; speedup vs baseline: 1.0605x; 1.0605x over previous
//
#include <hip/hip_runtime.h>
#include <hip/hip_bf16.h>
#include <math.h>

#define NF     16
#define INF    1024
#define NPROTO 4096
#define NROWS  16384

typedef __attribute__((ext_vector_type(8))) short short8;   // 8 bf16 (4 VGPRs)
typedef __attribute__((ext_vector_type(4))) float f32x4;
typedef __attribute__((ext_vector_type(2))) float f32x2;

__device__ __forceinline__ float bf16_rne(float x) {
    unsigned u = __float_as_uint(x);
    unsigned r = (u + 0x7FFFu + ((u >> 16) & 1u)) & 0xFFFF0000u;
    return __uint_as_float(r);
}
__device__ __forceinline__ unsigned short bf16_hi(float v) {
    unsigned u = __float_as_uint(v);
    return (unsigned short)((u + 0x7FFFu + ((u >> 16) & 1u)) >> 16);
}
// split f32 v into bf16 hi + bf16 lo (v ~= hi + lo)
__device__ __forceinline__ void split_bf16(float v, unsigned short& hi, unsigned short& lo) {
    unsigned u  = __float_as_uint(v);
    unsigned r  = u + 0x7FFFu + ((u >> 16) & 1u);
    hi = (unsigned short)(r >> 16);
    float hf = __uint_as_float(r & 0xFFFF0000u);
    lo = bf16_hi(v - hf);
}
__device__ __forceinline__ float sigmoid5(float z) {
    return 1.0f / (1.0f + __expf(-5.0f * z));
}

// ---- B-fragment precompute: feat -> bf16 hi/lo MFMA fragments ----
__global__ __launch_bounds__(256) void bfrag_kernel(
    const float* __restrict__ feat,
    unsigned short* __restrict__ BFh, unsigned short* __restrict__ BFl)
{
    const int t = blockIdx.x * 256 + threadIdx.x;    // 0..2047
    const int kstep = t >> 6, lane = t & 63;
    const int n = lane & 15, b = lane >> 4;
    const float* src = feat + (size_t)n * INF + kstep * 32 + b * 8;
    float4 v0 = *(const float4*)(src);
    float4 v1 = *(const float4*)(src + 4);
    unsigned short h[8], l[8];
    split_bf16(v0.x, h[0], l[0]); split_bf16(v0.y, h[1], l[1]);
    split_bf16(v0.z, h[2], l[2]); split_bf16(v0.w, h[3], l[3]);
    split_bf16(v1.x, h[4], l[4]); split_bf16(v1.y, h[5], l[5]);
    split_bf16(v1.z, h[6], l[6]); split_bf16(v1.w, h[7], l[7]);
#pragma unroll
    for (int e = 0; e < 8; ++e) { BFh[t * 8 + e] = h[e]; BFl[t * 8 + e] = l[e]; }
}

// ---- R25 prep: 8-wave K-split, STAGED loads (all loads issued before any
// convert/MFMA -> one latency exposure per wave), Ph hi-plane only ----
// Block = 512 thr = 8 waves; xe: wave w ksteps [4w,4w+4); pe: groups [2w,2w+2).
__global__ __launch_bounds__(512, 4) void prep(
    const float* __restrict__ x, const float* __restrict__ proto,
    const float* __restrict__ theta, const float* __restrict__ alpha,
    const float* __restrict__ beta,
    const unsigned short* __restrict__ BFh, const unsigned short* __restrict__ BFl,
    unsigned short* __restrict__ Ph,
    unsigned short* __restrict__ Xh, unsigned short* __restrict__ Xl)
{
    __shared__ f32x4 red[8][64];        // 8 KB partial-acc reduce
    const int lane = threadIdx.x & 63;
    const int w    = threadIdx.x >> 6;  // 0..7
    const int m = lane & 15, b = lane >> 4;
    const int blk = blockIdx.x;
    const bool is_pe = (blk < NPROTO / 16);
    const int rowbase = (is_pe ? blk : blk - NPROTO / 16) * 16;
    const float* rowp = (is_pe ? proto : x) + (size_t)(rowbase + m) * INF;

    f32x4 acc = {0.f, 0.f, 0.f, 0.f};

    if (is_pe) {
        // ---- stage: 2 groups x 4 float4 = 8 loads, all issued first ----
        float4 s[2][4];
#pragma unroll
        for (int gi = 0; gi < 2; ++gi) {
            const float* pg = rowp + (2 * w + gi) * 64 + b * 8;
            s[gi][0] = *(const float4*)(pg);
            s[gi][1] = *(const float4*)(pg + 4);
            s[gi][2] = *(const float4*)(pg + 32);
            s[gi][3] = *(const float4*)(pg + 36);
        }
#pragma unroll
        for (int gi = 0; gi < 2; ++gi) {
            const int g = 2 * w + gi;
            float w0 = bf16_rne(s[gi][0].x), w1 = bf16_rne(s[gi][0].y), w2 = bf16_rne(s[gi][0].z), w3 = bf16_rne(s[gi][0].w);
            float w4 = bf16_rne(s[gi][1].x), w5 = bf16_rne(s[gi][1].y), w6 = bf16_rne(s[gi][1].z), w7 = bf16_rne(s[gi][1].w);
            float w8 = bf16_rne(s[gi][2].x), w9 = bf16_rne(s[gi][2].y), wa = bf16_rne(s[gi][2].z), wb = bf16_rne(s[gi][2].w);
            float wc = bf16_rne(s[gi][3].x), wd = bf16_rne(s[gi][3].y), we = bf16_rne(s[gi][3].z), wf = bf16_rne(s[gi][3].w);
            float p0 = ((fabsf(w0) + fabsf(w1)) + fabsf(w2)) + fabsf(w3);
            float p1 = ((fabsf(w4) + fabsf(w5)) + fabsf(w6)) + fabsf(w7);
            float p2 = ((fabsf(w8) + fabsf(w9)) + fabsf(wa)) + fabsf(wb);
            float p3 = ((fabsf(wc) + fabsf(wd)) + fabsf(we)) + fabsf(wf);
            float p = ((p0 + p1) + p2) + p3;
            p += __shfl_xor(p, 16, 64);
            p += __shfl_xor(p, 32, 64);
            float scale = fmaxf(bf16_rne(p * (1.0f / 64.0f)), 1e-8f);
            float inv = 1.0f / scale;
            short8 A0, A1;
            A0[0] = (short)bf16_hi(fminf(fmaxf(rintf(bf16_rne(w0 * inv)), -1.f), 1.f) * scale);
            A0[1] = (short)bf16_hi(fminf(fmaxf(rintf(bf16_rne(w1 * inv)), -1.f), 1.f) * scale);
            A0[2] = (short)bf16_hi(fminf(fmaxf(rintf(bf16_rne(w2 * inv)), -1.f), 1.f) * scale);
            A0[3] = (short)bf16_hi(fminf(fmaxf(rintf(bf16_rne(w3 * inv)), -1.f), 1.f) * scale);
            A0[4] = (short)bf16_hi(fminf(fmaxf(rintf(bf16_rne(w4 * inv)), -1.f), 1.f) * scale);
            A0[5] = (short)bf16_hi(fminf(fmaxf(rintf(bf16_rne(w5 * inv)), -1.f), 1.f) * scale);
            A0[6] = (short)bf16_hi(fminf(fmaxf(rintf(bf16_rne(w6 * inv)), -1.f), 1.f) * scale);
            A0[7] = (short)bf16_hi(fminf(fmaxf(rintf(bf16_rne(w7 * inv)), -1.f), 1.f) * scale);
            A1[0] = (short)bf16_hi(fminf(fmaxf(rintf(bf16_rne(w8 * inv)), -1.f), 1.f) * scale);
            A1[1] = (short)bf16_hi(fminf(fmaxf(rintf(bf16_rne(w9 * inv)), -1.f), 1.f) * scale);
            A1[2] = (short)bf16_hi(fminf(fmaxf(rintf(bf16_rne(wa * inv)), -1.f), 1.f) * scale);
            A1[3] = (short)bf16_hi(fminf(fmaxf(rintf(bf16_rne(wb * inv)), -1.f), 1.f) * scale);
            A1[4] = (short)bf16_hi(fminf(fmaxf(rintf(bf16_rne(wc * inv)), -1.f), 1.f) * scale);
            A1[5] = (short)bf16_hi(fminf(fmaxf(rintf(bf16_rne(wd * inv)), -1.f), 1.f) * scale);
            A1[6] = (short)bf16_hi(fminf(fmaxf(rintf(bf16_rne(we * inv)), -1.f), 1.f) * scale);
            A1[7] = (short)bf16_hi(fminf(fmaxf(rintf(bf16_rne(wf * inv)), -1.f), 1.f) * scale);
            const short8 Bh0 = *(const short8*)(BFh + ((size_t)(2 * g) * 64 + lane) * 8);
            const short8 Bl0 = *(const short8*)(BFl + ((size_t)(2 * g) * 64 + lane) * 8);
            const short8 Bh1 = *(const short8*)(BFh + ((size_t)(2 * g + 1) * 64 + lane) * 8);
            const short8 Bl1 = *(const short8*)(BFl + ((size_t)(2 * g + 1) * 64 + lane) * 8);
            acc = __builtin_amdgcn_mfma_f32_16x16x32_bf16(A0, Bh0, acc, 0, 0, 0);
            acc = __builtin_amdgcn_mfma_f32_16x16x32_bf16(A0, Bl0, acc, 0, 0, 0);
            acc = __builtin_amdgcn_mfma_f32_16x16x32_bf16(A1, Bh1, acc, 0, 0, 0);
            acc = __builtin_amdgcn_mfma_f32_16x16x32_bf16(A1, Bl1, acc, 0, 0, 0);
        }
    } else {
        // ---- stage: 4 ksteps x 2 float4 = 8 loads, all issued first ----
        float4 s[4][2];
#pragma unroll
        for (int ki = 0; ki < 4; ++ki) {
            const float* pk = rowp + (4 * w + ki) * 32 + b * 8;
            s[ki][0] = *(const float4*)(pk);
            s[ki][1] = *(const float4*)(pk + 4);
        }
#pragma unroll
        for (int ki = 0; ki < 4; ++ki) {
            const int kstep = 4 * w + ki;
            unsigned short h0,l0,h1,l1,h2,l2,h3,l3,h4,l4,h5,l5,h6,l6,h7,l7;
            split_bf16(s[ki][0].x, h0, l0); split_bf16(s[ki][0].y, h1, l1);
            split_bf16(s[ki][0].z, h2, l2); split_bf16(s[ki][0].w, h3, l3);
            split_bf16(s[ki][1].x, h4, l4); split_bf16(s[ki][1].y, h5, l5);
            split_bf16(s[ki][1].z, h6, l6); split_bf16(s[ki][1].w, h7, l7);
            short8 Ah, Al;
            Ah[0]=(short)h0; Ah[1]=(short)h1; Ah[2]=(short)h2; Ah[3]=(short)h3;
            Ah[4]=(short)h4; Ah[5]=(short)h5; Ah[6]=(short)h6; Ah[7]=(short)h7;
            Al[0]=(short)l0; Al[1]=(short)l1; Al[2]=(short)l2; Al[3]=(short)l3;
            Al[4]=(short)l4; Al[5]=(short)l5; Al[6]=(short)l6; Al[7]=(short)l7;
            const short8 Bh = *(const short8*)(BFh + ((size_t)kstep * 64 + lane) * 8);
            const short8 Bl = *(const short8*)(BFl + ((size_t)kstep * 64 + lane) * 8);
            acc = __builtin_amdgcn_mfma_f32_16x16x32_bf16(Ah, Bh, acc, 0, 0, 0);
            acc = __builtin_amdgcn_mfma_f32_16x16x32_bf16(Ah, Bl, acc, 0, 0, 0);
            acc = __builtin_amdgcn_mfma_f32_16x16x32_bf16(Al, Bh, acc, 0, 0, 0);
            acc = __builtin_amdgcn_mfma_f32_16x16x32_bf16(Al, Bl, acc, 0, 0, 0);
        }
    }

    // ---- cross-wave K reduce (8 partials) ----
    red[w][lane] = acc;
    __syncthreads();
    if (w == 0) {
        f32x4 t0 = (red[0][lane] + red[1][lane]) + (red[2][lane] + red[3][lane]);
        f32x4 t1 = (red[4][lane] + red[5][lane]) + (red[6][lane] + red[7][lane]);
        f32x4 tot = t0 + t1;
        if (is_pe) {
            const float th = fabsf(theta[0]);
            const float al = fabsf(alpha[0]);
            const float be = fabsf(beta[0]);
#pragma unroll
            for (int reg = 0; reg < 4; ++reg) {
                const int row = rowbase + b * 4 + reg;
                float pf = tot[reg];
                float ps = sigmoid5(pf);
                float pa = pf * ps;
                Ph[row * 32 + m]      = bf16_hi(th * pa - al * (1.0f - ps));
                Ph[row * 32 + 16 + m] = bf16_hi(-be * pa);
            }
        } else {
#pragma unroll
            for (int reg = 0; reg < 4; ++reg) {
                const int row = rowbase + b * 4 + reg;
                float xf = tot[reg];
                float xs = sigmoid5(xf);
                unsigned short h0,l0,h1,l1;
                split_bf16(xf * xs, h0, l0);
                split_bf16(1.0f - xs, h1, l1);
                Xh[row * 32 + m]      = h0;  Xl[row * 32 + m]      = l0;
                Xh[row * 32 + 16 + m] = h1;  Xl[row * 32 + 16 + m] = l1;
            }
        }
    }
}

// ------- main: R23 body verbatim (43.2 us, write-bound at ~6.2 TB/s) -------
__global__ __launch_bounds__(64) void main_mm_mfma(
    const unsigned short* __restrict__ Xh, const unsigned short* __restrict__ Xl,
    const unsigned short* __restrict__ Ph,
    float* __restrict__ out)
{
    __shared__ float lds[16][128];      // 8 KiB, wave-private (1 wave/block)
    const int lane  = threadIdx.x & 63;
    const int m     = lane & 15;
    const int b     = lane >> 4;
    const int nbase = blockIdx.y * 16;
    const int ob    = blockIdx.x * 128;

    const size_t boff = (size_t)(nbase + m) * 32 + b * 8;
    const short8 Bh = *(const short8*)(Xh + boff);
    const short8 Bl = *(const short8*)(Xl + boff);

    const int wsw = 4 * (m & 7);
    float* myrow = &lds[m][0];
#pragma unroll
    for (int t = 0; t < 8; ++t) {
        const size_t aoff = (size_t)(ob + t * 16 + m) * 32 + b * 8;
        const short8 Ah = *(const short8*)(Ph + aoff);
        f32x4 acc = {0.f, 0.f, 0.f, 0.f};
        acc = __builtin_amdgcn_mfma_f32_16x16x32_bf16(Ah, Bh, acc, 0, 0, 0);
        acc = __builtin_amdgcn_mfma_f32_16x16x32_bf16(Ah, Bl, acc, 0, 0, 0);
        *(f32x4*)(myrow + ((t * 16 + b * 4) ^ wsw)) = acc;
    }

    const float* src = &lds[0][0];
#pragma unroll
    for (int r = 0; r < 16; ++r) {
        f32x2 v = *(const f32x2*)(src + r * 128 + ((lane * 2) ^ (4 * (r & 7))));
        f32x2* dst = (f32x2*)(out + (size_t)(nbase + r) * NPROTO + ob + lane * 2);
        __builtin_nontemporal_store(v, dst);
    }
}

extern "C" void kernel_launch(void* const* d_in, const int* in_sizes, int n_in,
                              void* d_out, int out_size, void* d_ws, size_t ws_size,
                              hipStream_t stream) {
    const float* x     = (const float*)d_in[0];
    const float* feat  = (const float*)d_in[1];
    const float* proto = (const float*)d_in[2];
    const float* theta = (const float*)d_in[3];
    const float* alpha = (const float*)d_in[4];
    const float* beta  = (const float*)d_in[5];
    float* out = (float*)d_out;

    unsigned short* Ph  = (unsigned short*)d_ws;          // 256 KiB
    unsigned short* Xh  = Ph + (size_t)NPROTO * 32;       // 1 MiB
    unsigned short* Xl  = Xh + (size_t)NROWS * 32;        // 1 MiB
    unsigned short* BFh = Xl + (size_t)NROWS * 32;        // 32 KiB
    unsigned short* BFl = BFh + (size_t)2048 * 8;         // 32 KiB

    bfrag_kernel<<<dim3(8), 256, 0, stream>>>(feat, BFh, BFl);
    prep<<<dim3(NPROTO / 16 + NROWS / 16), 512, 0, stream>>>(
        x, proto, theta, alpha, beta, BFh, BFl, Ph, Xh, Xl);
    main_mm_mfma<<<dim3(NPROTO / 128, NROWS / 16), 64, 0, stream>>>(Xh, Xl, Ph, out);
}

// Round 26
// 70.349 us; speedup vs baseline: 1.0660x; 1.0052x over previous
//
#include <hip/hip_runtime.h>
#include <hip/hip_bf16.h>
#include <math.h>

#define NF     16
#define INF    1024
#define NPROTO 4096
#define NROWS  16384

typedef __attribute__((ext_vector_type(8))) short short8;   // 8 bf16 (4 VGPRs)
typedef __attribute__((ext_vector_type(4))) float f32x4;
typedef __attribute__((ext_vector_type(2))) float f32x2;

__device__ __forceinline__ float bf16_rne(float x) {
    unsigned u = __float_as_uint(x);
    unsigned r = (u + 0x7FFFu + ((u >> 16) & 1u)) & 0xFFFF0000u;
    return __uint_as_float(r);
}
__device__ __forceinline__ unsigned short bf16_hi(float v) {
    unsigned u = __float_as_uint(v);
    return (unsigned short)((u + 0x7FFFu + ((u >> 16) & 1u)) >> 16);
}
// split f32 v into bf16 hi + bf16 lo (v ~= hi + lo)
__device__ __forceinline__ void split_bf16(float v, unsigned short& hi, unsigned short& lo) {
    unsigned u  = __float_as_uint(v);
    unsigned r  = u + 0x7FFFu + ((u >> 16) & 1u);
    hi = (unsigned short)(r >> 16);
    float hf = __uint_as_float(r & 0xFFFF0000u);
    lo = bf16_hi(v - hf);
}
__device__ __forceinline__ float sigmoid5(float z) {
    return 1.0f / (1.0f + __expf(-5.0f * z));
}

// inline B-fragment: same bits bfrag_kernel produced (same split of same feat)
__device__ __forceinline__ void make_bfrag(
    const float* __restrict__ feat, int kstep, int m, int b,
    short8& Bh, short8& Bl)
{
    const float* src = feat + (size_t)m * INF + kstep * 32 + b * 8;
    float4 v0 = *(const float4*)(src);
    float4 v1 = *(const float4*)(src + 4);
    unsigned short h, l;
    split_bf16(v0.x, h, l); Bh[0]=(short)h; Bl[0]=(short)l;
    split_bf16(v0.y, h, l); Bh[1]=(short)h; Bl[1]=(short)l;
    split_bf16(v0.z, h, l); Bh[2]=(short)h; Bl[2]=(short)l;
    split_bf16(v0.w, h, l); Bh[3]=(short)h; Bl[3]=(short)l;
    split_bf16(v1.x, h, l); Bh[4]=(short)h; Bl[4]=(short)l;
    split_bf16(v1.y, h, l); Bh[5]=(short)h; Bl[5]=(short)l;
    split_bf16(v1.z, h, l); Bh[6]=(short)h; Bl[6]=(short)l;
    split_bf16(v1.w, h, l); Bh[7]=(short)h; Bl[7]=(short)l;
}

// ---- R26 prep: R23 4-wave K-split body, INLINE B-fragments (no bfrag
// dispatch), Ph hi-plane only. Block 256 thr = 4 waves; xe: wave w ksteps
// [8w,8w+8); pe: groups [4w,4w+4). feat is L2-hot (64 KB).
__global__ __launch_bounds__(256, 4) void prep(
    const float* __restrict__ x, const float* __restrict__ proto,
    const float* __restrict__ feat,
    const float* __restrict__ theta, const float* __restrict__ alpha,
    const float* __restrict__ beta,
    unsigned short* __restrict__ Ph,
    unsigned short* __restrict__ Xh, unsigned short* __restrict__ Xl)
{
    __shared__ f32x4 red[4][64];        // 4 KB partial-acc reduce buffer
    const int lane = threadIdx.x & 63;
    const int w    = threadIdx.x >> 6;
    const int m = lane & 15, b = lane >> 4;
    const int blk = blockIdx.x;
    const bool is_pe = (blk < NPROTO / 16);
    const int rowbase = (is_pe ? blk : blk - NPROTO / 16) * 16;
    const float* rowp = (is_pe ? proto : x) + (size_t)(rowbase + m) * INF;

    f32x4 acc = {0.f, 0.f, 0.f, 0.f};

    if (is_pe) {
#pragma unroll
        for (int gi = 0; gi < 4; ++gi) {
            const int g = w * 4 + gi;   // 64-elem quant group; ksteps 2g, 2g+1
            const float* pg = rowp + g * 64 + b * 8;
            float4 v0 = *(const float4*)(pg);
            float4 v1 = *(const float4*)(pg + 4);
            float4 v2 = *(const float4*)(pg + 32);
            float4 v3 = *(const float4*)(pg + 36);
            float w0 = bf16_rne(v0.x), w1 = bf16_rne(v0.y), w2 = bf16_rne(v0.z), w3 = bf16_rne(v0.w);
            float w4 = bf16_rne(v1.x), w5 = bf16_rne(v1.y), w6 = bf16_rne(v1.z), w7 = bf16_rne(v1.w);
            float w8 = bf16_rne(v2.x), w9 = bf16_rne(v2.y), wa = bf16_rne(v2.z), wb = bf16_rne(v2.w);
            float wc = bf16_rne(v3.x), wd = bf16_rne(v3.y), we = bf16_rne(v3.z), wf = bf16_rne(v3.w);
            float p0 = ((fabsf(w0) + fabsf(w1)) + fabsf(w2)) + fabsf(w3);
            float p1 = ((fabsf(w4) + fabsf(w5)) + fabsf(w6)) + fabsf(w7);
            float p2 = ((fabsf(w8) + fabsf(w9)) + fabsf(wa)) + fabsf(wb);
            float p3 = ((fabsf(wc) + fabsf(wd)) + fabsf(we)) + fabsf(wf);
            float p = ((p0 + p1) + p2) + p3;
            p += __shfl_xor(p, 16, 64);
            p += __shfl_xor(p, 32, 64);
            float scale = fmaxf(bf16_rne(p * (1.0f / 64.0f)), 1e-8f);
            float inv = 1.0f / scale;
            short8 A0, A1;
            A0[0] = (short)bf16_hi(fminf(fmaxf(rintf(bf16_rne(w0 * inv)), -1.f), 1.f) * scale);
            A0[1] = (short)bf16_hi(fminf(fmaxf(rintf(bf16_rne(w1 * inv)), -1.f), 1.f) * scale);
            A0[2] = (short)bf16_hi(fminf(fmaxf(rintf(bf16_rne(w2 * inv)), -1.f), 1.f) * scale);
            A0[3] = (short)bf16_hi(fminf(fmaxf(rintf(bf16_rne(w3 * inv)), -1.f), 1.f) * scale);
            A0[4] = (short)bf16_hi(fminf(fmaxf(rintf(bf16_rne(w4 * inv)), -1.f), 1.f) * scale);
            A0[5] = (short)bf16_hi(fminf(fmaxf(rintf(bf16_rne(w5 * inv)), -1.f), 1.f) * scale);
            A0[6] = (short)bf16_hi(fminf(fmaxf(rintf(bf16_rne(w6 * inv)), -1.f), 1.f) * scale);
            A0[7] = (short)bf16_hi(fminf(fmaxf(rintf(bf16_rne(w7 * inv)), -1.f), 1.f) * scale);
            A1[0] = (short)bf16_hi(fminf(fmaxf(rintf(bf16_rne(w8 * inv)), -1.f), 1.f) * scale);
            A1[1] = (short)bf16_hi(fminf(fmaxf(rintf(bf16_rne(w9 * inv)), -1.f), 1.f) * scale);
            A1[2] = (short)bf16_hi(fminf(fmaxf(rintf(bf16_rne(wa * inv)), -1.f), 1.f) * scale);
            A1[3] = (short)bf16_hi(fminf(fmaxf(rintf(bf16_rne(wb * inv)), -1.f), 1.f) * scale);
            A1[4] = (short)bf16_hi(fminf(fmaxf(rintf(bf16_rne(wc * inv)), -1.f), 1.f) * scale);
            A1[5] = (short)bf16_hi(fminf(fmaxf(rintf(bf16_rne(wd * inv)), -1.f), 1.f) * scale);
            A1[6] = (short)bf16_hi(fminf(fmaxf(rintf(bf16_rne(we * inv)), -1.f), 1.f) * scale);
            A1[7] = (short)bf16_hi(fminf(fmaxf(rintf(bf16_rne(wf * inv)), -1.f), 1.f) * scale);
            short8 Bh0, Bl0, Bh1, Bl1;
            make_bfrag(feat, 2 * g,     m, b, Bh0, Bl0);
            make_bfrag(feat, 2 * g + 1, m, b, Bh1, Bl1);
            acc = __builtin_amdgcn_mfma_f32_16x16x32_bf16(A0, Bh0, acc, 0, 0, 0);
            acc = __builtin_amdgcn_mfma_f32_16x16x32_bf16(A0, Bl0, acc, 0, 0, 0);
            acc = __builtin_amdgcn_mfma_f32_16x16x32_bf16(A1, Bh1, acc, 0, 0, 0);
            acc = __builtin_amdgcn_mfma_f32_16x16x32_bf16(A1, Bl1, acc, 0, 0, 0);
        }
    } else {
#pragma unroll
        for (int ki = 0; ki < 8; ++ki) {
            const int kstep = w * 8 + ki;
            const float* pk = rowp + kstep * 32 + b * 8;
            float4 v0 = *(const float4*)(pk);
            float4 v1 = *(const float4*)(pk + 4);
            unsigned short h0,l0,h1,l1,h2,l2,h3,l3,h4,l4,h5,l5,h6,l6,h7,l7;
            split_bf16(v0.x, h0, l0); split_bf16(v0.y, h1, l1);
            split_bf16(v0.z, h2, l2); split_bf16(v0.w, h3, l3);
            split_bf16(v1.x, h4, l4); split_bf16(v1.y, h5, l5);
            split_bf16(v1.z, h6, l6); split_bf16(v1.w, h7, l7);
            short8 Ah, Al;
            Ah[0]=(short)h0; Ah[1]=(short)h1; Ah[2]=(short)h2; Ah[3]=(short)h3;
            Ah[4]=(short)h4; Ah[5]=(short)h5; Ah[6]=(short)h6; Ah[7]=(short)h7;
            Al[0]=(short)l0; Al[1]=(short)l1; Al[2]=(short)l2; Al[3]=(short)l3;
            Al[4]=(short)l4; Al[5]=(short)l5; Al[6]=(short)l6; Al[7]=(short)l7;
            short8 Bh, Bl;
            make_bfrag(feat, kstep, m, b, Bh, Bl);
            acc = __builtin_amdgcn_mfma_f32_16x16x32_bf16(Ah, Bh, acc, 0, 0, 0);
            acc = __builtin_amdgcn_mfma_f32_16x16x32_bf16(Ah, Bl, acc, 0, 0, 0);
            acc = __builtin_amdgcn_mfma_f32_16x16x32_bf16(Al, Bh, acc, 0, 0, 0);
            acc = __builtin_amdgcn_mfma_f32_16x16x32_bf16(Al, Bl, acc, 0, 0, 0);
        }
    }

    // ---- cross-wave K reduce ----
    red[w][lane] = acc;
    __syncthreads();
    if (w == 0) {
        f32x4 a0 = red[0][lane], a1 = red[1][lane], a2 = red[2][lane], a3 = red[3][lane];
        f32x4 tot = (a0 + a1) + (a2 + a3);
        if (is_pe) {
            const float th = fabsf(theta[0]);
            const float al = fabsf(alpha[0]);
            const float be = fabsf(beta[0]);
#pragma unroll
            for (int reg = 0; reg < 4; ++reg) {
                const int row = rowbase + b * 4 + reg;
                float pf = tot[reg];
                float ps = sigmoid5(pf);
                float pa = pf * ps;
                Ph[row * 32 + m]      = bf16_hi(th * pa - al * (1.0f - ps));
                Ph[row * 32 + 16 + m] = bf16_hi(-be * pa);
            }
        } else {
#pragma unroll
            for (int reg = 0; reg < 4; ++reg) {
                const int row = rowbase + b * 4 + reg;
                float xf = tot[reg];
                float xs = sigmoid5(xf);
                unsigned short h0,l0,h1,l1;
                split_bf16(xf * xs, h0, l0);
                split_bf16(1.0f - xs, h1, l1);
                Xh[row * 32 + m]      = h0;  Xl[row * 32 + m]      = l0;
                Xh[row * 32 + 16 + m] = h1;  Xl[row * 32 + 16 + m] = l1;
            }
        }
    }
}

// ------- main: R23 body verbatim (43.2 us, write-bound at ~6.2 TB/s) -------
__global__ __launch_bounds__(64) void main_mm_mfma(
    const unsigned short* __restrict__ Xh, const unsigned short* __restrict__ Xl,
    const unsigned short* __restrict__ Ph,
    float* __restrict__ out)
{
    __shared__ float lds[16][128];      // 8 KiB, wave-private (1 wave/block)
    const int lane  = threadIdx.x & 63;
    const int m     = lane & 15;
    const int b     = lane >> 4;
    const int nbase = blockIdx.y * 16;
    const int ob    = blockIdx.x * 128;

    const size_t boff = (size_t)(nbase + m) * 32 + b * 8;
    const short8 Bh = *(const short8*)(Xh + boff);
    const short8 Bl = *(const short8*)(Xl + boff);

    const int wsw = 4 * (m & 7);
    float* myrow = &lds[m][0];
#pragma unroll
    for (int t = 0; t < 8; ++t) {
        const size_t aoff = (size_t)(ob + t * 16 + m) * 32 + b * 8;
        const short8 Ah = *(const short8*)(Ph + aoff);
        f32x4 acc = {0.f, 0.f, 0.f, 0.f};
        acc = __builtin_amdgcn_mfma_f32_16x16x32_bf16(Ah, Bh, acc, 0, 0, 0);
        acc = __builtin_amdgcn_mfma_f32_16x16x32_bf16(Ah, Bl, acc, 0, 0, 0);
        *(f32x4*)(myrow + ((t * 16 + b * 4) ^ wsw)) = acc;
    }

    const float* src = &lds[0][0];
#pragma unroll
    for (int r = 0; r < 16; ++r) {
        f32x2 v = *(const f32x2*)(src + r * 128 + ((lane * 2) ^ (4 * (r & 7))));
        f32x2* dst = (f32x2*)(out + (size_t)(nbase + r) * NPROTO + ob + lane * 2);
        __builtin_nontemporal_store(v, dst);
    }
}

extern "C" void kernel_launch(void* const* d_in, const int* in_sizes, int n_in,
                              void* d_out, int out_size, void* d_ws, size_t ws_size,
                              hipStream_t stream) {
    const float* x     = (const float*)d_in[0];
    const float* feat  = (const float*)d_in[1];
    const float* proto = (const float*)d_in[2];
    const float* theta = (const float*)d_in[3];
    const float* alpha = (const float*)d_in[4];
    const float* beta  = (const float*)d_in[5];
    float* out = (float*)d_out;

    unsigned short* Ph = (unsigned short*)d_ws;          // 256 KiB
    unsigned short* Xh = Ph + (size_t)NPROTO * 32;       // 1 MiB
    unsigned short* Xl = Xh + (size_t)NROWS * 32;        // 1 MiB

    prep<<<dim3(NPROTO / 16 + NROWS / 16), 256, 0, stream>>>(
        x, proto, feat, theta, alpha, beta, Ph, Xh, Xl);
    main_mm_mfma<<<dim3(NPROTO / 128, NROWS / 16), 64, 0, stream>>>(Xh, Xl, Ph, out);
}